// Round 4
// baseline (220.549 us; speedup 1.0000x reference)
//
#include <hip/hip_runtime.h>

typedef __bf16 bf16x8 __attribute__((ext_vector_type(8)));
typedef float  floatx16 __attribute__((ext_vector_type(16)));

#define HW   56
#define NPIX 3136
#define CIN  128
#define COUT 256

// W2 layout: [cc(4)][tap(9)][cg(4)][oc(256)][j(8)], bf16. 576 KB of d_ws.
__global__ __launch_bounds__(256) void wt_transform_kernel(
        const float* __restrict__ Kw, __bf16* __restrict__ W2) {
    int idx = blockIdx.x * 256 + threadIdx.x;     // coalesced write
    int j     = idx & 7;
    int oc    = (idx >> 3) & 255;
    int cg    = (idx >> 11) & 3;
    int tapcc = idx >> 13;                        // cc*9 + tap
    int tap   = tapcc % 9;
    int cc    = tapcc / 9;
    int c = cc * 32 + cg * 8 + j;
    W2[idx] = (__bf16)Kw[oc * 1152 + c * 9 + tap];
}

// Xs buffer: [row(4)][wp(66)][slot(40)] bf16; slots 0..31 = ci, 32..39 pad.
// Stride 40 elems = 80 B -> conflict-free b128 reads and writes (verified R3:
// SQ_LDS_BANK_CONFLICT 4.1e6 -> 3.6e4).
#define XSBUF (4 * 2640)
__device__ __forceinline__ int xs_idx(int row, int wp, int cg) {
    return row * 2640 + wp * 40 + cg * 8;
}

// Block: 256 thr = 4 waves. Block tile: 128 oc x 128 pos (2 out-rows x 64 wpad).
// Wave: 64 oc x 64 pos (one out-row) -> 2mi x 2nj of 32x32x16, acc = 64 AGPR.
// R4: double-buffered Xs + register staging prefetch (1 barrier/cc) + depth-1
// A-load pipeline. R3 showed all pipes <21% busy -> latency/phase-lock bound.
__global__ __launch_bounds__(256, 3) void conv_kernel(
        const float* __restrict__ x, const __bf16* __restrict__ W2,
        const float* __restrict__ bias, float* __restrict__ out) {
    __shared__ __align__(16) __bf16 Xs[2 * XSBUF];   // 42.2 KB

    const int t    = threadIdx.x;
    const int nb   = blockIdx.x / 28;
    const int ht   = blockIdx.x % 28;
    const int h0   = ht * 2;
    const int ocb  = blockIdx.y * 128;

    const int wid  = t >> 6;
    const int lane = t & 63;
    const int half = lane >> 5;
    const int l31  = lane & 31;

    const int oc_base = ocb + (wid & 1) * 64;   // wave's 64-oc slice
    const int prow    = wid >> 1;               // wave's output row (0/1)

    // Staging map: thread -> (w = t&63, cg = t>>6); 4 rows x 8 c-strided loads.
    const int  sw     = t & 63;
    const int  sg     = t >> 6;
    const bool wvalid = sw < 56;

    // ---- issue cc=0 staging loads immediately (latency overlaps init) ----
    float sv[4][8];
    {
        const int cc = 0;
        #pragma unroll
        for (int row = 0; row < 4; ++row) {
            int hin = h0 - 1 + row;
            bool v = wvalid && (unsigned)hin < 56u;
            const float* src = x + (size_t)(nb * CIN + cc * 32 + sg * 8) * NPIX
                                 + hin * HW + sw;
            #pragma unroll
            for (int j = 0; j < 8; ++j)
                sv[row][j] = v ? src[j * NPIX] : 0.f;
        }
    }

    floatx16 acc[2][2];
    #pragma unroll
    for (int mi = 0; mi < 2; ++mi)
        #pragma unroll
        for (int nj = 0; nj < 2; ++nj)
            #pragma unroll
            for (int k = 0; k < 16; ++k)
                acc[mi][nj][k] = 0.f;

    // Zero halo columns (wp==0, wp in [57,66)) in BOTH buffers, written once.
    if (t < 160) {
        int cg   = t & 3;
        int rest = t >> 2;            // 0..39
        int row  = rest / 10;
        int zw   = rest % 10;
        int wp   = (zw == 0) ? 0 : (56 + zw);
        *(int4*)&Xs[xs_idx(row, wp, cg)]         = make_int4(0, 0, 0, 0);
        *(int4*)&Xs[XSBUF + xs_idx(row, wp, cg)] = make_int4(0, 0, 0, 0);
    }

    for (int cc = 0; cc < 4; ++cc) {
        __bf16* xb = &Xs[(cc & 1) * XSBUF];
        // Write staged registers -> buf[cc&1]. Safe w/o extra barrier: buf
        // [cc&1] was last read in compute(cc-2), which precedes barrier(cc-1)
        // in every wave's program order.
        if (wvalid) {
            #pragma unroll
            for (int row = 0; row < 4; ++row) {
                bf16x8 v;
                #pragma unroll
                for (int j = 0; j < 8; ++j) v[j] = (__bf16)sv[row][j];
                *(bf16x8*)&xb[xs_idx(row, 1 + sw, sg)] = v;
            }
        }
        __syncthreads();              // the ONLY barrier per cc

        // Issue next chunk's staging loads now; latency hides behind compute.
        if (cc < 3) {
            #pragma unroll
            for (int row = 0; row < 4; ++row) {
                int hin = h0 - 1 + row;
                bool v = wvalid && (unsigned)hin < 56u;
                const float* src = x + (size_t)(nb * CIN + (cc + 1) * 32 + sg * 8) * NPIX
                                     + hin * HW + sw;
                #pragma unroll
                for (int j = 0; j < 8; ++j)
                    sv[row][j] = v ? src[j * NPIX] : 0.f;
            }
        }

        // ---- compute: 18 iters (9 taps x 2 kc), depth-1 A pipeline ----
        const __bf16* wcc = W2 + (size_t)cc * 9 * (4 * 256 * 8);
        bf16x8 afr[2], afrN[2];
        #pragma unroll
        for (int mi = 0; mi < 2; ++mi)
            afr[mi] = *(const bf16x8*)(wcc + ((size_t)0 * (4 * 256 * 8))
                        + ((0 * 2 + half) * 256 + oc_base + mi * 32 + l31) * 8);
        #pragma unroll
        for (int it = 0; it < 18; ++it) {
            const int tap = it >> 1, kc = it & 1;
            const int r = tap / 3, s = tap % 3;
            const int itn = (it < 17) ? it + 1 : 17;
            const int tapn = itn >> 1, kcn = itn & 1;
            // prefetch next iter's A-fragments (L2-resident W2)
            #pragma unroll
            for (int mi = 0; mi < 2; ++mi)
                afrN[mi] = *(const bf16x8*)(wcc + (size_t)tapn * (4 * 256 * 8)
                            + ((kcn * 2 + half) * 256 + oc_base + mi * 32 + l31) * 8);
            bf16x8 bfr[2];
            #pragma unroll
            for (int nj = 0; nj < 2; ++nj) {
                int pw = nj * 32 + l31;
                bfr[nj] = *(const bf16x8*)&xb[xs_idx(prow + r, pw + s, kc * 2 + half)];
            }
            #pragma unroll
            for (int mi = 0; mi < 2; ++mi)
                #pragma unroll
                for (int nj = 0; nj < 2; ++nj)
                    acc[mi][nj] = __builtin_amdgcn_mfma_f32_32x32x16_bf16(
                        afr[mi], bfr[nj], acc[mi][nj], 0, 0, 0);
            afr[0] = afrN[0];
            afr[1] = afrN[1];
        }
    }

    // Epilogue: C/D 32x32 layout col=lane&31 (pos), row=(rg&3)+8*(rg>>2)+4*half.
    const float bv = bias[0];
    const int hout = h0 + prow;
    #pragma unroll
    for (int nj = 0; nj < 2; ++nj) {
        int pw = nj * 32 + l31;
        if (pw < 56) {
            #pragma unroll
            for (int mi = 0; mi < 2; ++mi) {
                #pragma unroll
                for (int rg = 0; rg < 16; ++rg) {
                    int oc = oc_base + mi * 32 + (rg & 3) + ((rg >> 2) << 3) + half * 4;
                    out[(size_t)(nb * COUT + oc) * NPIX + hout * HW + pw] = acc[mi][nj][rg] + bv;
                }
            }
        }
    }
}

extern "C" void kernel_launch(void* const* d_in, const int* in_sizes, int n_in,
                              void* d_out, int out_size, void* d_ws, size_t ws_size,
                              hipStream_t stream) {
    const float* x    = (const float*)d_in[0];
    const float* Kw   = (const float*)d_in[1];
    const float* bias = (const float*)d_in[2];
    float* out = (float*)d_out;
    __bf16* W2 = (__bf16*)d_ws;   // needs 589824 bytes of workspace

    wt_transform_kernel<<<dim3(1152), dim3(256), 0, stream>>>(Kw, W2);
    conv_kernel<<<dim3(32 * 28, 2), dim3(256), 0, stream>>>(x, W2, bias, out);
}